// Round 9
// baseline (149.062 us; speedup 1.0000x reference)
//
#include <hip/hip_runtime.h>
#include <math.h>

#define N_NODES 50000
#define N_EDGES 800000
#define IN_DIM 128
#define N_HEADS 4
#define OUT_DIM 32
#define PROJ_DIM 128   // N_HEADS * OUT_DIM
#define WSTR 144       // Wt LDS row stride in shorts (288 B, 16B-aligned)

#define NBIN 196       // ceil(50000/256): bin = src >> 8 (COARSE: partition locality)
#define BINCAP 5000    // edges per bin region (mean 4096, sigma ~64 -> 14 sigma)
#define NQBLK (NBIN * 4)   // 784 binsort blocks: one per 64-node QUARTER of a bin
#define QCAP 1408          // per-quarter csr capacity (mean 1024 + 12 sigma)
#define MAXDEG 64      // gather clamp (max expected deg ~38 for Poisson(16))

#define PROJ_BLKS 391                    // ceil(50000/128), 128 rows/block
#define PART_BLKS 391                    // 2048 edges per block
#define FUSE_BLKS (NQBLK + PROJ_BLKS)    // K2: binsort-quarter blocks, then proj

typedef short bf16x8 __attribute__((ext_vector_type(8)));
typedef float f32x4  __attribute__((ext_vector_type(4)));
typedef _Float16 h2  __attribute__((ext_vector_type(2)));

// fp32 -> bf16 bits with round-to-nearest-even (used for MFMA input staging)
__device__ __forceinline__ ushort f32_to_bf16(float f) {
    unsigned u = __float_as_uint(f);
    unsigned r = u + 0x7fffu + ((u >> 16) & 1u);
    return (ushort)(r >> 16);
}

__device__ __forceinline__ bf16x8 cvt8(float4 a, float4 b) {
    bf16x8 r;
    r[0] = (short)f32_to_bf16(a.x); r[1] = (short)f32_to_bf16(a.y);
    r[2] = (short)f32_to_bf16(a.z); r[3] = (short)f32_to_bf16(a.w);
    r[4] = (short)f32_to_bf16(b.x); r[5] = (short)f32_to_bf16(b.y);
    r[6] = (short)f32_to_bf16(b.z); r[7] = (short)f32_to_bf16(b.w);
    return r;
}

// f32 -> f16 bits (RTE). projT stored as f16: gather consumes via
// v_dot2_f32_f16, and f16's 10-bit mantissa beats bf16 for these O(1) values.
__device__ __forceinline__ ushort f32_to_f16(float f) {
    return __builtin_bit_cast(ushort, (_Float16)f);
}

// ---------------------------------------------------------------------------
// K1: partition — EXACT R7 version (196 coarse bins = proven write locality;
// R8 showed fine bins destroy it). 2048 edges/block, LDS histogram,
// 196 returning global atomics/block, packed slab stores.
// ---------------------------------------------------------------------------
__global__ __launch_bounds__(256) void partition_kernel(
    const int* __restrict__ ei, int* __restrict__ bin_cursor,
    unsigned* __restrict__ slab)
{
    __shared__ int cnt[256];
    __shared__ int gbase[256];

    const int tid = threadIdx.x;

    for (int t = tid; t < NBIN; t += 256) cnt[t] = 0;
    __syncthreads();

    const int ebase = blockIdx.x * 2048;
    unsigned srcv[8], tgtv[8];
    int rank[8];
#pragma unroll
    for (int i = 0; i < 8; ++i) {
        int e = ebase + i * 256 + tid;
        bool ok = e < N_EDGES;
        srcv[i] = ok ? (unsigned)ei[e] : 0u;
        tgtv[i] = ok ? (unsigned)ei[N_EDGES + e] : 0u;
        rank[i] = ok ? atomicAdd(&cnt[srcv[i] >> 8], 1) : -1;
    }
    __syncthreads();

    for (int t = tid; t < NBIN; t += 256)
        gbase[t] = atomicAdd(&bin_cursor[t], cnt[t]);   // 196/block global
    __syncthreads();

#pragma unroll
    for (int i = 0; i < 8; ++i) {
        if (rank[i] >= 0) {
            int bin = srcv[i] >> 8;
            int p = gbase[bin] + rank[i];
            if (p < BINCAP)
                slab[bin * BINCAP + p] = (tgtv[i] << 16) | (srcv[i] & 255u);
        }
    }
}

// ---------------------------------------------------------------------------
// K2: proj + binsort FUSED by block specialization.
//  blocks [0, NQBLK): QUARTER-binsort — block b handles bin b>>2, node
//    quarter b&3 (64 nodes). Scans the bin's full slab (~4096 edges,
//    L2-resident, redundant 4x read is ~13 MB total = trivial) and filters
//    to its quarter (~1024 edges): 64-counter LDS histogram, single-wave
//    scan, LDS scatter, coalesced dump. 784 well-occupied blocks (R7's 196
//    sub-occupancy fixed WITHOUT touching partition locality — R8 lesson).
//  blocks [NQBLK, FUSE_BLKS): proj = X @ W via bf16 MFMA 16x16x32; projT
//    epilogue stores f16 bits. (unchanged from R7)
// ---------------------------------------------------------------------------
__global__ __launch_bounds__(256) void fused_kernel(
    const float* __restrict__ X, const float* __restrict__ W,
    const float* __restrict__ att,
    const unsigned* __restrict__ slab, const int* __restrict__ bin_cursor,
    ushort* __restrict__ projT, float* __restrict__ s_src, float* __restrict__ s_tgt,
    ushort* __restrict__ csr, int* __restrict__ offs, int* __restrict__ deg)
{
    __shared__ ushort Wt[128 * WSTR];   // 36.9 KB; binsort blocks alias it

    const int tid = threadIdx.x;

    if (blockIdx.x < NQBLK) {
        // ------------------- quarter-binsort part ------------------------
        int*    cnt2 = (int*)Wt;                 // 64 ints
        int*    ex   = cnt2 + 64;                // 64 ints
        int*    tot  = ex + 64;                  // 1 int
        ushort* stgt = (ushort*)(tot + 4);       // 1408 ushorts (2.8 KB)

        const int b   = blockIdx.x;
        const int bin = b >> 2;
        const int qtr = b & 3;
        const int t   = tid;
        int n_e = bin_cursor[bin];
        n_e = (n_e < BINCAP) ? n_e : BINCAP;

        if (t < 64) cnt2[t] = 0;
        __syncthreads();

        unsigned pk[20];                   // (tgt<<16)|(rank<<8)|idx6
        int npk = 0;
        for (int i = t; i < n_e; i += 256) {
            unsigned v = slab[bin * BINCAP + i];
            int node8 = v & 255u;
            if ((node8 >> 6) == qtr) {     // filter to this quarter
                int idx = node8 & 63;
                int r = atomicAdd(&cnt2[idx], 1);
                r = (r < 255) ? r : 255;
                pk[npk++] = (v & 0xFFFF0000u) | ((unsigned)r << 8) | (unsigned)idx;
            }
        }
        __syncthreads();

        // single-wave inclusive scan over the 64 counters (wave 0 only;
        // fully active -> shuffles at full EXEC, safe)
        if (t < 64) {
            int v = cnt2[t];
            int x = v;
#pragma unroll
            for (int off = 1; off < 64; off <<= 1) {
                int y = __shfl_up(x, off);
                x += (t >= off) ? y : 0;
            }
            ex[t] = x - v;                 // exclusive prefix
            if (t == 63) *tot = x;         // quarter edge count
        }
        __syncthreads();

        for (int j = 0; j < npk; ++j) {
            unsigned pv = pk[j];
            int lpos = ex[pv & 63u] + (int)((pv >> 8) & 255u);
            if (lpos < QCAP) stgt[lpos] = (ushort)(pv >> 16);
        }
        __syncthreads();

        int qn = *tot;
        qn = (qn < QCAP) ? qn : QCAP;
        for (int i = t; i < qn; i += 256) csr[b * QCAP + i] = stgt[i];
        int node = bin * 256 + qtr * 64 + t;
        if (t < 64 && node < N_NODES) {
            offs[node] = b * QCAP + ex[t];
            deg[node]  = cnt2[t];
        }
        return;
    }

    // ------------------------- proj part ---------------------------------
    for (int idx = tid; idx < 64 * 128; idx += 256) {
        int kp = idx >> 7;
        int c  = idx & 127;
        float w0 = W[(2 * kp) * PROJ_DIM + c];
        float w1 = W[(2 * kp + 1) * PROJ_DIM + c];
        unsigned pr = (unsigned)f32_to_bf16(w0) | ((unsigned)f32_to_bf16(w1) << 16);
        *(unsigned*)&Wt[c * WSTR + 2 * kp] = pr;
    }
    __syncthreads();

    const int wv   = tid >> 6;
    const int lane = tid & 63;
    const int m = lane & 15;
    const int q = lane >> 4;
    const int rbase = (blockIdx.x - NQBLK) * 128;

    int arow0 = rbase + wv * 32 + m;
    int arow1 = arow0 + 16;
    arow0 = (arow0 < N_NODES) ? arow0 : N_NODES - 1;
    arow1 = (arow1 < N_NODES) ? arow1 : N_NODES - 1;
    const long long xb0 = (long long)arow0 * IN_DIM;
    const long long xb1 = (long long)arow1 * IN_DIM;

    f32x4 acc[2][8];
#pragma unroll
    for (int rt = 0; rt < 2; ++rt)
#pragma unroll
        for (int ct = 0; ct < 8; ++ct) acc[rt][ct] = (f32x4){0.f, 0.f, 0.f, 0.f};

#pragma unroll
    for (int ks = 0; ks < 4; ++ks) {
        const int k0 = ks * 32 + q * 8;
        float4 a0lo = *(const float4*)&X[xb0 + k0];
        float4 a0hi = *(const float4*)&X[xb0 + k0 + 4];
        float4 a1lo = *(const float4*)&X[xb1 + k0];
        float4 a1hi = *(const float4*)&X[xb1 + k0 + 4];
        bf16x8 afrag0 = cvt8(a0lo, a0hi);
        bf16x8 afrag1 = cvt8(a1lo, a1hi);
#pragma unroll
        for (int ct = 0; ct < 8; ++ct) {
            bf16x8 bfrag = *(const bf16x8*)&Wt[(ct * 16 + m) * WSTR + k0];
            acc[0][ct] = __builtin_amdgcn_mfma_f32_16x16x32_bf16(afrag0, bfrag, acc[0][ct], 0, 0, 0);
            acc[1][ct] = __builtin_amdgcn_mfma_f32_16x16x32_bf16(afrag1, bfrag, acc[1][ct], 0, 0, 0);
        }
    }

    const float as_lo = att[m],      as_hi = att[m + 16];
    const float at_lo = att[32 + m], at_hi = att[48 + m];

#pragma unroll
    for (int rt = 0; rt < 2; ++rt) {
        const int rowb = rbase + wv * 32 + rt * 16 + q * 4;
#pragma unroll
        for (int r = 0; r < 4; ++r) {
            const int row = rowb + r;
            float cl[4], ch[4];
#pragma unroll
            for (int h = 0; h < 4; ++h) {
                cl[h] = acc[rt][2 * h][r];
                ch[h] = acc[rt][2 * h + 1][r];
            }
            if (row < N_NODES) {
                ushort4 plo, phi;
                plo.x = f32_to_f16(cl[0]); plo.y = f32_to_f16(cl[1]);
                plo.z = f32_to_f16(cl[2]); plo.w = f32_to_f16(cl[3]);
                phi.x = f32_to_f16(ch[0]); phi.y = f32_to_f16(ch[1]);
                phi.z = f32_to_f16(ch[2]); phi.w = f32_to_f16(ch[3]);
                *(ushort4*)&projT[(long long)row * PROJ_DIM + m * 4] = plo;
                *(ushort4*)&projT[(long long)row * PROJ_DIM + (m + 16) * 4] = phi;
            }
            float ps[4], pt[4];
#pragma unroll
            for (int h = 0; h < 4; ++h) {
                ps[h] = cl[h] * as_lo + ch[h] * as_hi;
                pt[h] = cl[h] * at_lo + ch[h] * at_hi;
            }
#pragma unroll
            for (int off = 8; off > 0; off >>= 1) {
#pragma unroll
                for (int h = 0; h < 4; ++h) {
                    ps[h] += __shfl_down(ps[h], off, 16);
                    pt[h] += __shfl_down(pt[h], off, 16);
                }
            }
            if (m == 0 && row < N_NODES) {
                *(float4*)&s_src[row * N_HEADS] = make_float4(ps[0], ps[1], ps[2], ps[3]);
                *(float4*)&s_tgt[row * N_HEADS] = make_float4(pt[0], pt[1], pt[2], pt[3]);
            }
        }
    }
}

// ---------------------------------------------------------------------------
// K3: gather (unchanged from R7 — equal-best measured). LDS edge-table
// broadcast, 16 slots/pass, 8 outstanding projT loads, fdot2 accumulate.
// ---------------------------------------------------------------------------
__global__ __launch_bounds__(256) void gather_kernel(
    const int* __restrict__ deg, const int* __restrict__ offs,
    const ushort* __restrict__ csr,
    const float* __restrict__ s_src, const float* __restrict__ s_tgt,
    const ushort* __restrict__ projT, float* __restrict__ out)
{
    __shared__ uint4 edata[4][MAXDEG];     // 4 waves x 64 slots x 16 B = 4 KB

    const int wv   = threadIdx.x >> 6;
    const int lane = threadIdx.x & 63;
    const int node = blockIdx.x * 4 + wv;  // N_NODES = 12500*4

    int n = deg[node];
    n = (n < MAXDEG) ? n : MAXDEG;
    const int o = offs[node];

    uint4 ed = make_uint4(0u, 0u, 0u, 0u);
    if (lane < n) {
        int tgt = csr[o + lane];                            // coalesced ushort
        float4 ss = *(const float4*)&s_src[node * N_HEADS]; // wave-uniform
        float4 st = *(const float4*)&s_tgt[tgt * N_HEADS];  // parallel gather

        float sc[4] = { ss.x + st.x, ss.y + st.y, ss.z + st.z, ss.w + st.w };
        float mx = -1e30f;
#pragma unroll
        for (int h = 0; h < 4; ++h) {
            sc[h] = (sc[h] > 0.0f) ? sc[h] : 0.01f * sc[h];  // leaky_relu
            mx = fmaxf(mx, sc[h]);
        }
        float sum = 0.0f;
#pragma unroll
        for (int h = 0; h < 4; ++h) {
            sc[h] = __expf(sc[h] - mx);
            sum += sc[h];
        }
        float inv = 0.25f / sum;     // softmax normalize * head-mean

        h2 a01, a23;
        a01.x = (_Float16)(sc[0] * inv);
        a01.y = (_Float16)(sc[1] * inv);
        a23.x = (_Float16)(sc[2] * inv);
        a23.y = (_Float16)(sc[3] * inv);
        ed.x = (unsigned)tgt;
        ed.y = __builtin_bit_cast(unsigned, a01);
        ed.z = __builtin_bit_cast(unsigned, a23);
    }
    edata[wv][lane] = ed;            // all 64 lanes write (dead slots zeroed)
    // no barrier: same wave produces and consumes (lgkmcnt ordering)

    const int d    = lane & 31;
    const int half = lane >> 5;

    float acc0 = 0.0f, acc1 = 0.0f, acc2 = 0.0f, acc3 = 0.0f;

    // 16 edge slots per iteration (8 per half), 8 outstanding projT gathers
    // per lane; slot metadata via broadcast ds_read_b128.
    for (int j = 0; j < n; j += 16) {
        uint4 s[8];
#pragma unroll
        for (int u = 0; u < 8; ++u)
            s[u] = edata[wv][j + 2 * u + half];   // half-uniform broadcast
        uint2 p[8];
#pragma unroll
        for (int u = 0; u < 8; ++u)
            p[u] = *(const uint2*)&projT[(long long)s[u].x * PROJ_DIM + d * 4];
#pragma unroll
        for (int u = 0; u < 8; ++u) {
            h2 a  = __builtin_bit_cast(h2, s[u].y);
            h2 b  = __builtin_bit_cast(h2, s[u].z);
            h2 lo = __builtin_bit_cast(h2, p[u].x);
            h2 hi = __builtin_bit_cast(h2, p[u].y);
            float* accp = (u & 1) ? ((u & 2) ? &acc3 : &acc1)
                                  : ((u & 2) ? &acc2 : &acc0);
            float tt = *accp;
#if __has_builtin(__builtin_amdgcn_fdot2)
            tt = __builtin_amdgcn_fdot2(a, lo, tt, false);   // v_dot2_f32_f16
            tt = __builtin_amdgcn_fdot2(b, hi, tt, false);
#else
            tt = fmaf((float)a.x, (float)lo.x, tt);          // v_fma_mix_f32
            tt = fmaf((float)a.y, (float)lo.y, tt);
            tt = fmaf((float)b.x, (float)hi.x, tt);
            tt = fmaf((float)b.y, (float)hi.y, tt);
#endif
            *accp = tt;
        }
    }

    float acc = (acc0 + acc1) + (acc2 + acc3);
    acc += __shfl_down(acc, 32);      // combine the two halves (width 64)
    if (lane < 32) out[node * OUT_DIM + d] = acc;
}

extern "C" void kernel_launch(void* const* d_in, const int* in_sizes, int n_in,
                              void* d_out, int out_size, void* d_ws, size_t ws_size,
                              hipStream_t stream) {
    const float* X   = (const float*)d_in[0];
    const int*   ei  = (const int*)d_in[1];
    const float* W   = (const float*)d_in[2];
    const float* att = (const float*)d_in[3];
    float* out = (float*)d_out;

    // workspace layout, total ~21 MB
    char* p = (char*)d_ws;
    ushort* projT   = (ushort*)p;   p += (size_t)N_NODES * PROJ_DIM * 2;  // 12.8 MB
    float* s_src    = (float*)p;    p += (size_t)N_NODES * N_HEADS * 4;   // 0.8 MB
    float* s_tgt    = (float*)p;    p += (size_t)N_NODES * N_HEADS * 4;   // 0.8 MB
    unsigned* slab  = (unsigned*)p; p += (size_t)NBIN * BINCAP * 4;       // 3.92 MB
    ushort* csr     = (ushort*)p;   p += (size_t)NQBLK * QCAP * 2;        // 2.21 MB
    int* offs       = (int*)p;      p += (size_t)N_NODES * 4;             // 0.2 MB
    int* deg        = (int*)p;      p += (size_t)N_NODES * 4;             // 0.2 MB
    int* bin_cursor = (int*)p;      p += 256 * 4;

    (void)hipMemsetAsync(bin_cursor, 0, 256 * sizeof(int), stream);

    partition_kernel<<<PART_BLKS, 256, 0, stream>>>(ei, bin_cursor, slab);

    fused_kernel<<<FUSE_BLKS, 256, 0, stream>>>(
        X, W, att, slab, bin_cursor, projT, s_src, s_tgt, csr, offs, deg);

    gather_kernel<<<N_NODES / 4, 256, 0, stream>>>(
        deg, offs, csr, s_src, s_tgt, projT, out);
}

// Round 10
// 138.636 us; speedup vs baseline: 1.0752x; 1.0752x over previous
//
#include <hip/hip_runtime.h>
#include <math.h>

#define N_NODES 50000
#define N_EDGES 800000
#define IN_DIM 128
#define N_HEADS 4
#define OUT_DIM 32
#define PROJ_DIM 128   // N_HEADS * OUT_DIM
#define WSTR 144       // Wt LDS row stride in shorts (288 B, 16B-aligned)

#define NBIN 196       // ceil(50000/256): bin = src >> 8 (coarse: partition locality)
#define BINCAP 5000    // edges per bin region (mean 4096, sigma ~64 -> 14 sigma)
#define MAXDEG 64      // gather clamp (max expected deg ~38 for Poisson(16))

#define PROJ_BLKS 391                    // ceil(50000/128), 128 rows/block
#define PART_BLKS 391                    // 2048 edges per block
#define FUSE_BLKS (NBIN + PROJ_BLKS)     // K2: binsort blocks first, then proj

typedef short bf16x8 __attribute__((ext_vector_type(8)));
typedef float f32x4  __attribute__((ext_vector_type(4)));
typedef _Float16 h2  __attribute__((ext_vector_type(2)));

// fp32 -> bf16 bits with round-to-nearest-even (used for MFMA input staging)
__device__ __forceinline__ ushort f32_to_bf16(float f) {
    unsigned u = __float_as_uint(f);
    unsigned r = u + 0x7fffu + ((u >> 16) & 1u);
    return (ushort)(r >> 16);
}

__device__ __forceinline__ bf16x8 cvt8(float4 a, float4 b) {
    bf16x8 r;
    r[0] = (short)f32_to_bf16(a.x); r[1] = (short)f32_to_bf16(a.y);
    r[2] = (short)f32_to_bf16(a.z); r[3] = (short)f32_to_bf16(a.w);
    r[4] = (short)f32_to_bf16(b.x); r[5] = (short)f32_to_bf16(b.y);
    r[6] = (short)f32_to_bf16(b.z); r[7] = (short)f32_to_bf16(b.w);
    return r;
}

// f32 -> f16 bits (RTE). projT stored as f16: gather consumes via
// v_dot2_f32_f16, and f16's 10-bit mantissa beats bf16 for these O(1) values.
__device__ __forceinline__ ushort f32_to_f16(float f) {
    return __builtin_bit_cast(ushort, (_Float16)f);
}

// ---------------------------------------------------------------------------
// K1: partition — EXACT R7 version (196 coarse bins = proven write locality;
// R8/R9 showed finer granularity loses). 2048 edges/block, LDS histogram,
// 196 returning global atomics/block, packed slab stores.
// ---------------------------------------------------------------------------
__global__ __launch_bounds__(256) void partition_kernel(
    const int* __restrict__ ei, int* __restrict__ bin_cursor,
    unsigned* __restrict__ slab)
{
    __shared__ int cnt[256];
    __shared__ int gbase[256];

    const int tid = threadIdx.x;

    for (int t = tid; t < NBIN; t += 256) cnt[t] = 0;
    __syncthreads();

    const int ebase = blockIdx.x * 2048;
    unsigned srcv[8], tgtv[8];
    int rank[8];
#pragma unroll
    for (int i = 0; i < 8; ++i) {
        int e = ebase + i * 256 + tid;
        bool ok = e < N_EDGES;
        srcv[i] = ok ? (unsigned)ei[e] : 0u;
        tgtv[i] = ok ? (unsigned)ei[N_EDGES + e] : 0u;
        rank[i] = ok ? atomicAdd(&cnt[srcv[i] >> 8], 1) : -1;
    }
    __syncthreads();

    for (int t = tid; t < NBIN; t += 256)
        gbase[t] = atomicAdd(&bin_cursor[t], cnt[t]);   // 196/block global
    __syncthreads();

#pragma unroll
    for (int i = 0; i < 8; ++i) {
        if (rank[i] >= 0) {
            int bin = srcv[i] >> 8;
            int p = gbase[bin] + rank[i];
            if (p < BINCAP)
                slab[bin * BINCAP + p] = (tgtv[i] << 16) | (srcv[i] & 255u);
        }
    }
}

// ---------------------------------------------------------------------------
// K2: proj + binsort FUSED by block specialization — EXACT R7 version.
//  blocks [0, NBIN): binsort one bin each (LDS aliased onto Wt).
//  blocks [NBIN, FUSE_BLKS): proj = X @ W via bf16 MFMA 16x16x32; projT
//  epilogue stores f16 bits.
// ---------------------------------------------------------------------------
__global__ __launch_bounds__(256) void fused_kernel(
    const float* __restrict__ X, const float* __restrict__ W,
    const float* __restrict__ att,
    const unsigned* __restrict__ slab, const int* __restrict__ bin_cursor,
    ushort* __restrict__ projT, float* __restrict__ s_src, float* __restrict__ s_tgt,
    ushort* __restrict__ csr, int* __restrict__ offs, int* __restrict__ deg)
{
    __shared__ ushort Wt[128 * WSTR];   // 36.9 KB; binsort blocks alias it

    const int tid = threadIdx.x;

    if (blockIdx.x < NBIN) {
        // ----------------------- binsort part ----------------------------
        int*    cnt2 = (int*)Wt;                 // 256 ints @ 0
        int*    ex   = cnt2 + 256;               // 256 ints @ 1 KB
        int*    wsum = ex + 256;                 // 4 ints   @ 2 KB
        ushort* stgt = (ushort*)(wsum + 8);      // 10 KB    @ 2080 B (fits 36.9 KB)

        const int b = blockIdx.x;
        const int t = tid;
        const int lane = t & 63;
        const int wid  = t >> 6;
        int n_e = bin_cursor[b];
        n_e = (n_e < BINCAP) ? n_e : BINCAP;

        cnt2[t] = 0;
        __syncthreads();

        unsigned pk[20];                   // (tgt<<16)|(rank<<8)|node8
        int npk = 0;
        for (int i = t; i < n_e; i += 256) {
            unsigned v = slab[b * BINCAP + i];
            int node8 = v & 255u;
            int r = atomicAdd(&cnt2[node8], 1);
            r = (r < 255) ? r : 255;
            pk[npk++] = (v & 0xFFFF0000u) | ((unsigned)r << 8) | (unsigned)node8;
        }
        __syncthreads();

        // wave-level inclusive scan over 64 lanes (shuffles unconditional)
        const int v = cnt2[t];
        int x = v;
#pragma unroll
        for (int off = 1; off < 64; off <<= 1) {
            int y = __shfl_up(x, off);
            x += (lane >= off) ? y : 0;
        }
        if (lane == 63) wsum[wid] = x;
        __syncthreads();
        int add = 0;
#pragma unroll
        for (int w = 0; w < 4; ++w) add += (w < wid) ? wsum[w] : 0;
        const int myex = x + add - v;       // exclusive prefix
        const int mycnt = v;
        ex[t] = myex;
        __syncthreads();

        for (int j = 0; j < npk; ++j) {
            unsigned pv = pk[j];
            int lpos = ex[pv & 255u] + (int)((pv >> 8) & 255u);
            if (lpos < BINCAP) stgt[lpos] = (ushort)(pv >> 16);
        }
        __syncthreads();

        for (int i = t; i < n_e; i += 256) csr[b * BINCAP + i] = stgt[i];
        int node = b * 256 + t;
        if (node < N_NODES) {
            offs[node] = b * BINCAP + myex;
            deg[node]  = mycnt;
        }
        return;
    }

    // ------------------------- proj part ---------------------------------
    for (int idx = tid; idx < 64 * 128; idx += 256) {
        int kp = idx >> 7;
        int c  = idx & 127;
        float w0 = W[(2 * kp) * PROJ_DIM + c];
        float w1 = W[(2 * kp + 1) * PROJ_DIM + c];
        unsigned pr = (unsigned)f32_to_bf16(w0) | ((unsigned)f32_to_bf16(w1) << 16);
        *(unsigned*)&Wt[c * WSTR + 2 * kp] = pr;
    }
    __syncthreads();

    const int wv   = tid >> 6;
    const int lane = tid & 63;
    const int m = lane & 15;
    const int q = lane >> 4;
    const int rbase = (blockIdx.x - NBIN) * 128;

    int arow0 = rbase + wv * 32 + m;
    int arow1 = arow0 + 16;
    arow0 = (arow0 < N_NODES) ? arow0 : N_NODES - 1;
    arow1 = (arow1 < N_NODES) ? arow1 : N_NODES - 1;
    const long long xb0 = (long long)arow0 * IN_DIM;
    const long long xb1 = (long long)arow1 * IN_DIM;

    f32x4 acc[2][8];
#pragma unroll
    for (int rt = 0; rt < 2; ++rt)
#pragma unroll
        for (int ct = 0; ct < 8; ++ct) acc[rt][ct] = (f32x4){0.f, 0.f, 0.f, 0.f};

#pragma unroll
    for (int ks = 0; ks < 4; ++ks) {
        const int k0 = ks * 32 + q * 8;
        float4 a0lo = *(const float4*)&X[xb0 + k0];
        float4 a0hi = *(const float4*)&X[xb0 + k0 + 4];
        float4 a1lo = *(const float4*)&X[xb1 + k0];
        float4 a1hi = *(const float4*)&X[xb1 + k0 + 4];
        bf16x8 afrag0 = cvt8(a0lo, a0hi);
        bf16x8 afrag1 = cvt8(a1lo, a1hi);
#pragma unroll
        for (int ct = 0; ct < 8; ++ct) {
            bf16x8 bfrag = *(const bf16x8*)&Wt[(ct * 16 + m) * WSTR + k0];
            acc[0][ct] = __builtin_amdgcn_mfma_f32_16x16x32_bf16(afrag0, bfrag, acc[0][ct], 0, 0, 0);
            acc[1][ct] = __builtin_amdgcn_mfma_f32_16x16x32_bf16(afrag1, bfrag, acc[1][ct], 0, 0, 0);
        }
    }

    const float as_lo = att[m],      as_hi = att[m + 16];
    const float at_lo = att[32 + m], at_hi = att[48 + m];

#pragma unroll
    for (int rt = 0; rt < 2; ++rt) {
        const int rowb = rbase + wv * 32 + rt * 16 + q * 4;
#pragma unroll
        for (int r = 0; r < 4; ++r) {
            const int row = rowb + r;
            float cl[4], ch[4];
#pragma unroll
            for (int h = 0; h < 4; ++h) {
                cl[h] = acc[rt][2 * h][r];
                ch[h] = acc[rt][2 * h + 1][r];
            }
            if (row < N_NODES) {
                ushort4 plo, phi;
                plo.x = f32_to_f16(cl[0]); plo.y = f32_to_f16(cl[1]);
                plo.z = f32_to_f16(cl[2]); plo.w = f32_to_f16(cl[3]);
                phi.x = f32_to_f16(ch[0]); phi.y = f32_to_f16(ch[1]);
                phi.z = f32_to_f16(ch[2]); phi.w = f32_to_f16(ch[3]);
                *(ushort4*)&projT[(long long)row * PROJ_DIM + m * 4] = plo;
                *(ushort4*)&projT[(long long)row * PROJ_DIM + (m + 16) * 4] = phi;
            }
            float ps[4], pt[4];
#pragma unroll
            for (int h = 0; h < 4; ++h) {
                ps[h] = cl[h] * as_lo + ch[h] * as_hi;
                pt[h] = cl[h] * at_lo + ch[h] * at_hi;
            }
#pragma unroll
            for (int off = 8; off > 0; off >>= 1) {
#pragma unroll
                for (int h = 0; h < 4; ++h) {
                    ps[h] += __shfl_down(ps[h], off, 16);
                    pt[h] += __shfl_down(pt[h], off, 16);
                }
            }
            if (m == 0 && row < N_NODES) {
                *(float4*)&s_src[row * N_HEADS] = make_float4(ps[0], ps[1], ps[2], ps[3]);
                *(float4*)&s_tgt[row * N_HEADS] = make_float4(pt[0], pt[1], pt[2], pt[3]);
            }
        }
    }
}

// ---------------------------------------------------------------------------
// K3: gather v6 — R7 structure + SOFTWARE-PIPELINED double pass for deg>16.
//   n<=16 (57% of nodes): takes ONLY the final 16-slot pass — byte-identical
//   schedule to R7 (no regression risk on the majority path).
//   n>=17 (43%): 32-slot iterations issue 16 projT loads (two 8-batches)
//   before the first fdot consumes any — the second batch's latency hides
//   under the first instead of a fully-dependent second pass.
// ---------------------------------------------------------------------------
__global__ __launch_bounds__(256) void gather_kernel(
    const int* __restrict__ deg, const int* __restrict__ offs,
    const ushort* __restrict__ csr,
    const float* __restrict__ s_src, const float* __restrict__ s_tgt,
    const ushort* __restrict__ projT, float* __restrict__ out)
{
    __shared__ uint4 edata[4][MAXDEG];     // 4 waves x 64 slots x 16 B = 4 KB

    const int wv   = threadIdx.x >> 6;
    const int lane = threadIdx.x & 63;
    const int node = blockIdx.x * 4 + wv;  // N_NODES = 12500*4

    int n = deg[node];
    n = (n < MAXDEG) ? n : MAXDEG;
    const int o = offs[node];

    uint4 ed = make_uint4(0u, 0u, 0u, 0u);
    if (lane < n) {
        int tgt = csr[o + lane];                            // coalesced ushort
        float4 ss = *(const float4*)&s_src[node * N_HEADS]; // wave-uniform
        float4 st = *(const float4*)&s_tgt[tgt * N_HEADS];  // parallel gather

        float sc[4] = { ss.x + st.x, ss.y + st.y, ss.z + st.z, ss.w + st.w };
        float mx = -1e30f;
#pragma unroll
        for (int h = 0; h < 4; ++h) {
            sc[h] = (sc[h] > 0.0f) ? sc[h] : 0.01f * sc[h];  // leaky_relu
            mx = fmaxf(mx, sc[h]);
        }
        float sum = 0.0f;
#pragma unroll
        for (int h = 0; h < 4; ++h) {
            sc[h] = __expf(sc[h] - mx);
            sum += sc[h];
        }
        float inv = 0.25f / sum;     // softmax normalize * head-mean

        h2 a01, a23;
        a01.x = (_Float16)(sc[0] * inv);
        a01.y = (_Float16)(sc[1] * inv);
        a23.x = (_Float16)(sc[2] * inv);
        a23.y = (_Float16)(sc[3] * inv);
        ed.x = (unsigned)tgt;
        ed.y = __builtin_bit_cast(unsigned, a01);
        ed.z = __builtin_bit_cast(unsigned, a23);
    }
    edata[wv][lane] = ed;            // all 64 lanes write (dead slots zeroed)
    // no barrier: same wave produces and consumes (lgkmcnt ordering)

    const int d    = lane & 31;
    const int half = lane >> 5;

    float acc0 = 0.0f, acc1 = 0.0f, acc2 = 0.0f, acc3 = 0.0f;

    int j = 0;
    // ---- pipelined 32-slot iterations (only entered when n >= 17) ----
    for (; j + 16 < n; j += 32) {
        uint4 sA[8];
#pragma unroll
        for (int u = 0; u < 8; ++u)
            sA[u] = edata[wv][j + 2 * u + half];
        uint2 pA[8];
#pragma unroll
        for (int u = 0; u < 8; ++u)
            pA[u] = *(const uint2*)&projT[(long long)sA[u].x * PROJ_DIM + d * 4];
        uint4 sB[8];
#pragma unroll
        for (int u = 0; u < 8; ++u)
            sB[u] = edata[wv][j + 16 + 2 * u + half];
        uint2 pB[8];
#pragma unroll
        for (int u = 0; u < 8; ++u)
            pB[u] = *(const uint2*)&projT[(long long)sB[u].x * PROJ_DIM + d * 4];
#pragma unroll
        for (int u = 0; u < 8; ++u) {
            h2 a  = __builtin_bit_cast(h2, sA[u].y);
            h2 b  = __builtin_bit_cast(h2, sA[u].z);
            h2 lo = __builtin_bit_cast(h2, pA[u].x);
            h2 hi = __builtin_bit_cast(h2, pA[u].y);
            float* accp = (u & 1) ? ((u & 2) ? &acc3 : &acc1)
                                  : ((u & 2) ? &acc2 : &acc0);
            float tt = *accp;
#if __has_builtin(__builtin_amdgcn_fdot2)
            tt = __builtin_amdgcn_fdot2(a, lo, tt, false);
            tt = __builtin_amdgcn_fdot2(b, hi, tt, false);
#else
            tt = fmaf((float)a.x, (float)lo.x, tt);
            tt = fmaf((float)a.y, (float)lo.y, tt);
            tt = fmaf((float)b.x, (float)hi.x, tt);
            tt = fmaf((float)b.y, (float)hi.y, tt);
#endif
            *accp = tt;
        }
#pragma unroll
        for (int u = 0; u < 8; ++u) {
            h2 a  = __builtin_bit_cast(h2, sB[u].y);
            h2 b  = __builtin_bit_cast(h2, sB[u].z);
            h2 lo = __builtin_bit_cast(h2, pB[u].x);
            h2 hi = __builtin_bit_cast(h2, pB[u].y);
            float* accp = (u & 1) ? ((u & 2) ? &acc3 : &acc1)
                                  : ((u & 2) ? &acc2 : &acc0);
            float tt = *accp;
#if __has_builtin(__builtin_amdgcn_fdot2)
            tt = __builtin_amdgcn_fdot2(a, lo, tt, false);
            tt = __builtin_amdgcn_fdot2(b, hi, tt, false);
#else
            tt = fmaf((float)a.x, (float)lo.x, tt);
            tt = fmaf((float)a.y, (float)lo.y, tt);
            tt = fmaf((float)b.x, (float)hi.x, tt);
            tt = fmaf((float)b.y, (float)hi.y, tt);
#endif
            *accp = tt;
        }
    }
    // ---- final 16-slot pass (remaining <= 16 slots; R7-identical) ----
    for (; j < n; j += 16) {
        uint4 s[8];
#pragma unroll
        for (int u = 0; u < 8; ++u)
            s[u] = edata[wv][j + 2 * u + half];   // half-uniform broadcast
        uint2 p[8];
#pragma unroll
        for (int u = 0; u < 8; ++u)
            p[u] = *(const uint2*)&projT[(long long)s[u].x * PROJ_DIM + d * 4];
#pragma unroll
        for (int u = 0; u < 8; ++u) {
            h2 a  = __builtin_bit_cast(h2, s[u].y);
            h2 b  = __builtin_bit_cast(h2, s[u].z);
            h2 lo = __builtin_bit_cast(h2, p[u].x);
            h2 hi = __builtin_bit_cast(h2, p[u].y);
            float* accp = (u & 1) ? ((u & 2) ? &acc3 : &acc1)
                                  : ((u & 2) ? &acc2 : &acc0);
            float tt = *accp;
#if __has_builtin(__builtin_amdgcn_fdot2)
            tt = __builtin_amdgcn_fdot2(a, lo, tt, false);   // v_dot2_f32_f16
            tt = __builtin_amdgcn_fdot2(b, hi, tt, false);
#else
            tt = fmaf((float)a.x, (float)lo.x, tt);          // v_fma_mix_f32
            tt = fmaf((float)a.y, (float)lo.y, tt);
            tt = fmaf((float)b.x, (float)hi.x, tt);
            tt = fmaf((float)b.y, (float)hi.y, tt);
#endif
            *accp = tt;
        }
    }

    float acc = (acc0 + acc1) + (acc2 + acc3);
    acc += __shfl_down(acc, 32);      // combine the two halves (width 64)
    if (lane < 32) out[node * OUT_DIM + d] = acc;
}

extern "C" void kernel_launch(void* const* d_in, const int* in_sizes, int n_in,
                              void* d_out, int out_size, void* d_ws, size_t ws_size,
                              hipStream_t stream) {
    const float* X   = (const float*)d_in[0];
    const int*   ei  = (const int*)d_in[1];
    const float* W   = (const float*)d_in[2];
    const float* att = (const float*)d_in[3];
    float* out = (float*)d_out;

    // workspace layout, total ~20.8 MB
    char* p = (char*)d_ws;
    ushort* projT   = (ushort*)p;   p += (size_t)N_NODES * PROJ_DIM * 2;  // 12.8 MB
    float* s_src    = (float*)p;    p += (size_t)N_NODES * N_HEADS * 4;   // 0.8 MB
    float* s_tgt    = (float*)p;    p += (size_t)N_NODES * N_HEADS * 4;   // 0.8 MB
    unsigned* slab  = (unsigned*)p; p += (size_t)NBIN * BINCAP * 4;       // 3.92 MB
    ushort* csr     = (ushort*)p;   p += (size_t)NBIN * BINCAP * 2;       // 1.96 MB
    int* offs       = (int*)p;      p += (size_t)N_NODES * 4;             // 0.2 MB
    int* deg        = (int*)p;      p += (size_t)N_NODES * 4;             // 0.2 MB
    int* bin_cursor = (int*)p;      p += 256 * 4;

    (void)hipMemsetAsync(bin_cursor, 0, 256 * sizeof(int), stream);

    partition_kernel<<<PART_BLKS, 256, 0, stream>>>(ei, bin_cursor, slab);

    fused_kernel<<<FUSE_BLKS, 256, 0, stream>>>(
        X, W, att, slab, bin_cursor, projT, s_src, s_tgt, csr, offs, deg);

    gather_kernel<<<N_NODES / 4, 256, 0, stream>>>(
        deg, offs, csr, s_src, s_tgt, projT, out);
}

// Round 11
// 136.960 us; speedup vs baseline: 1.0884x; 1.0122x over previous
//
#include <hip/hip_runtime.h>
#include <math.h>

#define N_NODES 50000
#define N_EDGES 800000
#define IN_DIM 128
#define N_HEADS 4
#define OUT_DIM 32
#define PROJ_DIM 128   // N_HEADS * OUT_DIM
#define WSTR 144       // Wt LDS row stride in shorts (288 B, 16B-aligned)

#define NBIN 196       // ceil(50000/256): bin = src >> 8 (coarse: partition locality)
#define BINCAP 5000    // edges per bin region (mean 4096, sigma ~64 -> 14 sigma)
#define MAXDEG 64      // gather clamp (max expected deg ~38 for Poisson(16))

#define PROJ_BLKS 391                    // ceil(50000/128), 128 rows/block
#define PART_BLKS 391                    // 2048 edges per block
#define FUSE_BLKS (NBIN + PROJ_BLKS)     // K2: binsort blocks first, then proj

typedef short bf16x8 __attribute__((ext_vector_type(8)));
typedef float f32x4  __attribute__((ext_vector_type(4)));
typedef _Float16 h2  __attribute__((ext_vector_type(2)));

// fp32 -> bf16 bits with round-to-nearest-even (used for MFMA input staging)
__device__ __forceinline__ ushort f32_to_bf16(float f) {
    unsigned u = __float_as_uint(f);
    unsigned r = u + 0x7fffu + ((u >> 16) & 1u);
    return (ushort)(r >> 16);
}

__device__ __forceinline__ bf16x8 cvt8(float4 a, float4 b) {
    bf16x8 r;
    r[0] = (short)f32_to_bf16(a.x); r[1] = (short)f32_to_bf16(a.y);
    r[2] = (short)f32_to_bf16(a.z); r[3] = (short)f32_to_bf16(a.w);
    r[4] = (short)f32_to_bf16(b.x); r[5] = (short)f32_to_bf16(b.y);
    r[6] = (short)f32_to_bf16(b.z); r[7] = (short)f32_to_bf16(b.w);
    return r;
}

// f32 -> f16 bits (RTE). projT stored as f16: gather consumes via
// v_dot2_f32_f16, and f16's 10-bit mantissa beats bf16 for these O(1) values.
__device__ __forceinline__ ushort f32_to_f16(float f) {
    return __builtin_bit_cast(ushort, (_Float16)f);
}

// ---------------------------------------------------------------------------
// K1: partition — EXACT R7 version (196 coarse bins = proven write locality;
// R8/R9 showed finer granularity loses). 2048 edges/block, LDS histogram,
// 196 returning global atomics/block, packed slab stores.
// ---------------------------------------------------------------------------
__global__ __launch_bounds__(256) void partition_kernel(
    const int* __restrict__ ei, int* __restrict__ bin_cursor,
    unsigned* __restrict__ slab)
{
    __shared__ int cnt[256];
    __shared__ int gbase[256];

    const int tid = threadIdx.x;

    for (int t = tid; t < NBIN; t += 256) cnt[t] = 0;
    __syncthreads();

    const int ebase = blockIdx.x * 2048;
    unsigned srcv[8], tgtv[8];
    int rank[8];
#pragma unroll
    for (int i = 0; i < 8; ++i) {
        int e = ebase + i * 256 + tid;
        bool ok = e < N_EDGES;
        srcv[i] = ok ? (unsigned)ei[e] : 0u;
        tgtv[i] = ok ? (unsigned)ei[N_EDGES + e] : 0u;
        rank[i] = ok ? atomicAdd(&cnt[srcv[i] >> 8], 1) : -1;
    }
    __syncthreads();

    for (int t = tid; t < NBIN; t += 256)
        gbase[t] = atomicAdd(&bin_cursor[t], cnt[t]);   // 196/block global
    __syncthreads();

#pragma unroll
    for (int i = 0; i < 8; ++i) {
        if (rank[i] >= 0) {
            int bin = srcv[i] >> 8;
            int p = gbase[bin] + rank[i];
            if (p < BINCAP)
                slab[bin * BINCAP + p] = (tgtv[i] << 16) | (srcv[i] & 255u);
        }
    }
}

// ---------------------------------------------------------------------------
// K2: proj + binsort FUSED by block specialization — EXACT R7 version.
//  blocks [0, NBIN): binsort one bin each (LDS aliased onto Wt).
//  blocks [NBIN, FUSE_BLKS): proj = X @ W via bf16 MFMA 16x16x32; projT
//  epilogue stores f16 bits.
// ---------------------------------------------------------------------------
__global__ __launch_bounds__(256) void fused_kernel(
    const float* __restrict__ X, const float* __restrict__ W,
    const float* __restrict__ att,
    const unsigned* __restrict__ slab, const int* __restrict__ bin_cursor,
    ushort* __restrict__ projT, float* __restrict__ s_src, float* __restrict__ s_tgt,
    ushort* __restrict__ csr, int* __restrict__ offs, int* __restrict__ deg)
{
    __shared__ ushort Wt[128 * WSTR];   // 36.9 KB; binsort blocks alias it

    const int tid = threadIdx.x;

    if (blockIdx.x < NBIN) {
        // ----------------------- binsort part ----------------------------
        int*    cnt2 = (int*)Wt;                 // 256 ints @ 0
        int*    ex   = cnt2 + 256;               // 256 ints @ 1 KB
        int*    wsum = ex + 256;                 // 4 ints   @ 2 KB
        ushort* stgt = (ushort*)(wsum + 8);      // 10 KB    @ 2080 B (fits 36.9 KB)

        const int b = blockIdx.x;
        const int t = tid;
        const int lane = t & 63;
        const int wid  = t >> 6;
        int n_e = bin_cursor[b];
        n_e = (n_e < BINCAP) ? n_e : BINCAP;

        cnt2[t] = 0;
        __syncthreads();

        unsigned pk[20];                   // (tgt<<16)|(rank<<8)|node8
        int npk = 0;
        for (int i = t; i < n_e; i += 256) {
            unsigned v = slab[b * BINCAP + i];
            int node8 = v & 255u;
            int r = atomicAdd(&cnt2[node8], 1);
            r = (r < 255) ? r : 255;
            pk[npk++] = (v & 0xFFFF0000u) | ((unsigned)r << 8) | (unsigned)node8;
        }
        __syncthreads();

        // wave-level inclusive scan over 64 lanes (shuffles unconditional)
        const int v = cnt2[t];
        int x = v;
#pragma unroll
        for (int off = 1; off < 64; off <<= 1) {
            int y = __shfl_up(x, off);
            x += (lane >= off) ? y : 0;
        }
        if (lane == 63) wsum[wid] = x;
        __syncthreads();
        int add = 0;
#pragma unroll
        for (int w = 0; w < 4; ++w) add += (w < wid) ? wsum[w] : 0;
        const int myex = x + add - v;       // exclusive prefix
        const int mycnt = v;
        ex[t] = myex;
        __syncthreads();

        for (int j = 0; j < npk; ++j) {
            unsigned pv = pk[j];
            int lpos = ex[pv & 255u] + (int)((pv >> 8) & 255u);
            if (lpos < BINCAP) stgt[lpos] = (ushort)(pv >> 16);
        }
        __syncthreads();

        for (int i = t; i < n_e; i += 256) csr[b * BINCAP + i] = stgt[i];
        int node = b * 256 + t;
        if (node < N_NODES) {
            offs[node] = b * BINCAP + myex;
            deg[node]  = mycnt;
        }
        return;
    }

    // ------------------------- proj part ---------------------------------
    for (int idx = tid; idx < 64 * 128; idx += 256) {
        int kp = idx >> 7;
        int c  = idx & 127;
        float w0 = W[(2 * kp) * PROJ_DIM + c];
        float w1 = W[(2 * kp + 1) * PROJ_DIM + c];
        unsigned pr = (unsigned)f32_to_bf16(w0) | ((unsigned)f32_to_bf16(w1) << 16);
        *(unsigned*)&Wt[c * WSTR + 2 * kp] = pr;
    }
    __syncthreads();

    const int wv   = tid >> 6;
    const int lane = tid & 63;
    const int m = lane & 15;
    const int q = lane >> 4;
    const int rbase = (blockIdx.x - NBIN) * 128;

    int arow0 = rbase + wv * 32 + m;
    int arow1 = arow0 + 16;
    arow0 = (arow0 < N_NODES) ? arow0 : N_NODES - 1;
    arow1 = (arow1 < N_NODES) ? arow1 : N_NODES - 1;
    const long long xb0 = (long long)arow0 * IN_DIM;
    const long long xb1 = (long long)arow1 * IN_DIM;

    f32x4 acc[2][8];
#pragma unroll
    for (int rt = 0; rt < 2; ++rt)
#pragma unroll
        for (int ct = 0; ct < 8; ++ct) acc[rt][ct] = (f32x4){0.f, 0.f, 0.f, 0.f};

#pragma unroll
    for (int ks = 0; ks < 4; ++ks) {
        const int k0 = ks * 32 + q * 8;
        float4 a0lo = *(const float4*)&X[xb0 + k0];
        float4 a0hi = *(const float4*)&X[xb0 + k0 + 4];
        float4 a1lo = *(const float4*)&X[xb1 + k0];
        float4 a1hi = *(const float4*)&X[xb1 + k0 + 4];
        bf16x8 afrag0 = cvt8(a0lo, a0hi);
        bf16x8 afrag1 = cvt8(a1lo, a1hi);
#pragma unroll
        for (int ct = 0; ct < 8; ++ct) {
            bf16x8 bfrag = *(const bf16x8*)&Wt[(ct * 16 + m) * WSTR + k0];
            acc[0][ct] = __builtin_amdgcn_mfma_f32_16x16x32_bf16(afrag0, bfrag, acc[0][ct], 0, 0, 0);
            acc[1][ct] = __builtin_amdgcn_mfma_f32_16x16x32_bf16(afrag1, bfrag, acc[1][ct], 0, 0, 0);
        }
    }

    const float as_lo = att[m],      as_hi = att[m + 16];
    const float at_lo = att[32 + m], at_hi = att[48 + m];

#pragma unroll
    for (int rt = 0; rt < 2; ++rt) {
        const int rowb = rbase + wv * 32 + rt * 16 + q * 4;
#pragma unroll
        for (int r = 0; r < 4; ++r) {
            const int row = rowb + r;
            float cl[4], ch[4];
#pragma unroll
            for (int h = 0; h < 4; ++h) {
                cl[h] = acc[rt][2 * h][r];
                ch[h] = acc[rt][2 * h + 1][r];
            }
            if (row < N_NODES) {
                ushort4 plo, phi;
                plo.x = f32_to_f16(cl[0]); plo.y = f32_to_f16(cl[1]);
                plo.z = f32_to_f16(cl[2]); plo.w = f32_to_f16(cl[3]);
                phi.x = f32_to_f16(ch[0]); phi.y = f32_to_f16(ch[1]);
                phi.z = f32_to_f16(ch[2]); phi.w = f32_to_f16(ch[3]);
                *(ushort4*)&projT[(long long)row * PROJ_DIM + m * 4] = plo;
                *(ushort4*)&projT[(long long)row * PROJ_DIM + (m + 16) * 4] = phi;
            }
            float ps[4], pt[4];
#pragma unroll
            for (int h = 0; h < 4; ++h) {
                ps[h] = cl[h] * as_lo + ch[h] * as_hi;
                pt[h] = cl[h] * at_lo + ch[h] * at_hi;
            }
#pragma unroll
            for (int off = 8; off > 0; off >>= 1) {
#pragma unroll
                for (int h = 0; h < 4; ++h) {
                    ps[h] += __shfl_down(ps[h], off, 16);
                    pt[h] += __shfl_down(pt[h], off, 16);
                }
            }
            if (m == 0 && row < N_NODES) {
                *(float4*)&s_src[row * N_HEADS] = make_float4(ps[0], ps[1], ps[2], ps[3]);
                *(float4*)&s_tgt[row * N_HEADS] = make_float4(pt[0], pt[1], pt[2], pt[3]);
            }
        }
    }
}

// ---------------------------------------------------------------------------
// K3: gather v7 — QUARTER-WAVE per edge (16 lanes x 16 B = 2 dims x 4 heads).
//   A 32-slot pass issues the same 8 loads/lane as R7's 16-slot pass but
//   covers 2x the edges: deg in (16,32] (~35% of nodes) drops from 2
//   dependent passes to 1; deg<=16 is instruction-neutral (dead slots read
//   the L2-hot row 0 with alpha=0 — R2 proved masking loads is worse).
//   Edata reads: 4 consecutive uint4 addrs x 16-lane broadcast, conflict-
//   free. Epilogue: two unconditional shfl_down (32,16) quarter-combines,
//   lanes 0-15 store float2 (128 B coalesced). Prep identical to R7.
// ---------------------------------------------------------------------------
__global__ __launch_bounds__(256) void gather_kernel(
    const int* __restrict__ deg, const int* __restrict__ offs,
    const ushort* __restrict__ csr,
    const float* __restrict__ s_src, const float* __restrict__ s_tgt,
    const ushort* __restrict__ projT, float* __restrict__ out)
{
    __shared__ uint4 edata[4][MAXDEG];     // 4 waves x 64 slots x 16 B = 4 KB

    const int wv   = threadIdx.x >> 6;
    const int lane = threadIdx.x & 63;
    const int node = blockIdx.x * 4 + wv;  // N_NODES = 12500*4

    int n = deg[node];
    n = (n < MAXDEG) ? n : MAXDEG;
    const int o = offs[node];

    uint4 ed = make_uint4(0u, 0u, 0u, 0u);
    if (lane < n) {
        int tgt = csr[o + lane];                            // coalesced ushort
        float4 ss = *(const float4*)&s_src[node * N_HEADS]; // wave-uniform
        float4 st = *(const float4*)&s_tgt[tgt * N_HEADS];  // parallel gather

        float sc[4] = { ss.x + st.x, ss.y + st.y, ss.z + st.z, ss.w + st.w };
        float mx = -1e30f;
#pragma unroll
        for (int h = 0; h < 4; ++h) {
            sc[h] = (sc[h] > 0.0f) ? sc[h] : 0.01f * sc[h];  // leaky_relu
            mx = fmaxf(mx, sc[h]);
        }
        float sum = 0.0f;
#pragma unroll
        for (int h = 0; h < 4; ++h) {
            sc[h] = __expf(sc[h] - mx);
            sum += sc[h];
        }
        float inv = 0.25f / sum;     // softmax normalize * head-mean

        h2 a01, a23;
        a01.x = (_Float16)(sc[0] * inv);
        a01.y = (_Float16)(sc[1] * inv);
        a23.x = (_Float16)(sc[2] * inv);
        a23.y = (_Float16)(sc[3] * inv);
        ed.x = (unsigned)tgt;
        ed.y = __builtin_bit_cast(unsigned, a01);
        ed.z = __builtin_bit_cast(unsigned, a23);
    }
    edata[wv][lane] = ed;            // all 64 lanes write (dead slots zeroed)
    // no barrier: same wave produces and consumes (lgkmcnt ordering)

    const int k = lane & 15;         // dim-pair index: this lane owns dims 2k, 2k+1
    const int q = lane >> 4;         // quarter: edge-slot offset within group of 4

    // two accumulators per dim, rotated on u&1 to break the dependency chain
    float a0 = 0.0f, b0 = 0.0f;      // dim 2k
    float a1 = 0.0f, b1 = 0.0f;      // dim 2k+1

    // 32 edge slots per iteration: quarter q takes slots j+4u+q, u=0..7.
    // 8 outstanding 16 B projT gathers per lane (same queue depth as R7,
    // double the edge coverage).
    for (int j = 0; j < n; j += 32) {
        uint4 s[8];
#pragma unroll
        for (int u = 0; u < 8; ++u)
            s[u] = edata[wv][j + 4 * u + q];   // quarter-uniform broadcast
        uint4 p[8];
#pragma unroll
        for (int u = 0; u < 8; ++u)
            p[u] = *(const uint4*)&projT[(long long)s[u].x * PROJ_DIM + k * 8];
#pragma unroll
        for (int u = 0; u < 8; ++u) {
            h2 al = __builtin_bit_cast(h2, s[u].y);   // alpha h0,h1
            h2 ah = __builtin_bit_cast(h2, s[u].z);   // alpha h2,h3
            h2 v0 = __builtin_bit_cast(h2, p[u].x);   // dim 2k,   heads 0,1
            h2 v1 = __builtin_bit_cast(h2, p[u].y);   // dim 2k,   heads 2,3
            h2 v2 = __builtin_bit_cast(h2, p[u].z);   // dim 2k+1, heads 0,1
            h2 v3 = __builtin_bit_cast(h2, p[u].w);   // dim 2k+1, heads 2,3
            float* p0 = (u & 1) ? &b0 : &a0;
            float* p1 = (u & 1) ? &b1 : &a1;
            float t0 = *p0, t1 = *p1;
#if __has_builtin(__builtin_amdgcn_fdot2)
            t0 = __builtin_amdgcn_fdot2(al, v0, t0, false);
            t0 = __builtin_amdgcn_fdot2(ah, v1, t0, false);
            t1 = __builtin_amdgcn_fdot2(al, v2, t1, false);
            t1 = __builtin_amdgcn_fdot2(ah, v3, t1, false);
#else
            t0 = fmaf((float)al.x, (float)v0.x, t0);
            t0 = fmaf((float)al.y, (float)v0.y, t0);
            t0 = fmaf((float)ah.x, (float)v1.x, t0);
            t0 = fmaf((float)ah.y, (float)v1.y, t0);
            t1 = fmaf((float)al.x, (float)v2.x, t1);
            t1 = fmaf((float)al.y, (float)v2.y, t1);
            t1 = fmaf((float)ah.x, (float)v3.x, t1);
            t1 = fmaf((float)ah.y, (float)v3.y, t1);
#endif
            *p0 = t0; *p1 = t1;
        }
    }

    float acc0 = a0 + b0;
    float acc1 = a1 + b1;
    // combine the 4 quarters (all shuffles unconditional, full EXEC)
    acc0 += __shfl_down(acc0, 32);
    acc1 += __shfl_down(acc1, 32);
    acc0 += __shfl_down(acc0, 16);
    acc1 += __shfl_down(acc1, 16);
    if (lane < 16) {
        float2 v = make_float2(acc0, acc1);
        *(float2*)&out[node * OUT_DIM + 2 * k] = v;
    }
}

extern "C" void kernel_launch(void* const* d_in, const int* in_sizes, int n_in,
                              void* d_out, int out_size, void* d_ws, size_t ws_size,
                              hipStream_t stream) {
    const float* X   = (const float*)d_in[0];
    const int*   ei  = (const int*)d_in[1];
    const float* W   = (const float*)d_in[2];
    const float* att = (const float*)d_in[3];
    float* out = (float*)d_out;

    // workspace layout, total ~20.8 MB
    char* p = (char*)d_ws;
    ushort* projT   = (ushort*)p;   p += (size_t)N_NODES * PROJ_DIM * 2;  // 12.8 MB
    float* s_src    = (float*)p;    p += (size_t)N_NODES * N_HEADS * 4;   // 0.8 MB
    float* s_tgt    = (float*)p;    p += (size_t)N_NODES * N_HEADS * 4;   // 0.8 MB
    unsigned* slab  = (unsigned*)p; p += (size_t)NBIN * BINCAP * 4;       // 3.92 MB
    ushort* csr     = (ushort*)p;   p += (size_t)NBIN * BINCAP * 2;       // 1.96 MB
    int* offs       = (int*)p;      p += (size_t)N_NODES * 4;             // 0.2 MB
    int* deg        = (int*)p;      p += (size_t)N_NODES * 4;             // 0.2 MB
    int* bin_cursor = (int*)p;      p += 256 * 4;

    (void)hipMemsetAsync(bin_cursor, 0, 256 * sizeof(int), stream);

    partition_kernel<<<PART_BLKS, 256, 0, stream>>>(ei, bin_cursor, slab);

    fused_kernel<<<FUSE_BLKS, 256, 0, stream>>>(
        X, W, att, slab, bin_cursor, projT, s_src, s_tgt, csr, offs, deg);

    gather_kernel<<<N_NODES / 4, 256, 0, stream>>>(
        deg, offs, csr, s_src, s_tgt, projT, out);
}

// Round 12
// 136.468 us; speedup vs baseline: 1.0923x; 1.0036x over previous
//
#include <hip/hip_runtime.h>
#include <math.h>

#define N_NODES 50000
#define N_EDGES 800000
#define IN_DIM 128
#define N_HEADS 4
#define OUT_DIM 32
#define PROJ_DIM 128   // N_HEADS * OUT_DIM
#define WSTR 144       // Wt LDS row stride in shorts (288 B, 16B-aligned)

#define NBIN 196       // ceil(50000/256): bin = src >> 8 (coarse: partition locality)
#define BINCAP 5000    // edges per bin region (mean 4096, sigma ~64 -> 14 sigma)
#define MAXDEG 64      // gather clamp (max expected deg ~38 for Poisson(16))

#define PROJ_BLKS 391                    // ceil(50000/128), 128 rows/block
#define PART_BLKS 391                    // 2048 edges per block
#define FUSE_BLKS (NBIN + PROJ_BLKS)     // K2: binsort blocks first, then proj

#define NGROUPS 12500                    // node groups of 4 (one per wave-quad)
#define GATHER_BLKS 2048                 // grid-stride: 2048*4 waves = 32 waves/CU

typedef short bf16x8 __attribute__((ext_vector_type(8)));
typedef float f32x4  __attribute__((ext_vector_type(4)));
typedef _Float16 h2  __attribute__((ext_vector_type(2)));

// fp32 -> bf16 bits with round-to-nearest-even (used for MFMA input staging)
__device__ __forceinline__ ushort f32_to_bf16(float f) {
    unsigned u = __float_as_uint(f);
    unsigned r = u + 0x7fffu + ((u >> 16) & 1u);
    return (ushort)(r >> 16);
}

__device__ __forceinline__ bf16x8 cvt8(float4 a, float4 b) {
    bf16x8 r;
    r[0] = (short)f32_to_bf16(a.x); r[1] = (short)f32_to_bf16(a.y);
    r[2] = (short)f32_to_bf16(a.z); r[3] = (short)f32_to_bf16(a.w);
    r[4] = (short)f32_to_bf16(b.x); r[5] = (short)f32_to_bf16(b.y);
    r[6] = (short)f32_to_bf16(b.z); r[7] = (short)f32_to_bf16(b.w);
    return r;
}

// f32 -> f16 bits (RTE). projT stored as f16: gather consumes via
// v_dot2_f32_f16, and f16's 10-bit mantissa beats bf16 for these O(1) values.
__device__ __forceinline__ ushort f32_to_f16(float f) {
    return __builtin_bit_cast(ushort, (_Float16)f);
}

// ---------------------------------------------------------------------------
// K1: partition — EXACT R7 version (196 coarse bins = proven write locality;
// R8/R9 showed finer granularity loses). 2048 edges/block, LDS histogram,
// 196 returning global atomics/block, packed slab stores.
// ---------------------------------------------------------------------------
__global__ __launch_bounds__(256) void partition_kernel(
    const int* __restrict__ ei, int* __restrict__ bin_cursor,
    unsigned* __restrict__ slab)
{
    __shared__ int cnt[256];
    __shared__ int gbase[256];

    const int tid = threadIdx.x;

    for (int t = tid; t < NBIN; t += 256) cnt[t] = 0;
    __syncthreads();

    const int ebase = blockIdx.x * 2048;
    unsigned srcv[8], tgtv[8];
    int rank[8];
#pragma unroll
    for (int i = 0; i < 8; ++i) {
        int e = ebase + i * 256 + tid;
        bool ok = e < N_EDGES;
        srcv[i] = ok ? (unsigned)ei[e] : 0u;
        tgtv[i] = ok ? (unsigned)ei[N_EDGES + e] : 0u;
        rank[i] = ok ? atomicAdd(&cnt[srcv[i] >> 8], 1) : -1;
    }
    __syncthreads();

    for (int t = tid; t < NBIN; t += 256)
        gbase[t] = atomicAdd(&bin_cursor[t], cnt[t]);   // 196/block global
    __syncthreads();

#pragma unroll
    for (int i = 0; i < 8; ++i) {
        if (rank[i] >= 0) {
            int bin = srcv[i] >> 8;
            int p = gbase[bin] + rank[i];
            if (p < BINCAP)
                slab[bin * BINCAP + p] = (tgtv[i] << 16) | (srcv[i] & 255u);
        }
    }
}

// ---------------------------------------------------------------------------
// K2: proj + binsort FUSED by block specialization — EXACT R7 version.
//  blocks [0, NBIN): binsort one bin each (LDS aliased onto Wt).
//  blocks [NBIN, FUSE_BLKS): proj = X @ W via bf16 MFMA 16x16x32; projT
//  epilogue stores f16 bits.
// ---------------------------------------------------------------------------
__global__ __launch_bounds__(256) void fused_kernel(
    const float* __restrict__ X, const float* __restrict__ W,
    const float* __restrict__ att,
    const unsigned* __restrict__ slab, const int* __restrict__ bin_cursor,
    ushort* __restrict__ projT, float* __restrict__ s_src, float* __restrict__ s_tgt,
    ushort* __restrict__ csr, int* __restrict__ offs, int* __restrict__ deg)
{
    __shared__ ushort Wt[128 * WSTR];   // 36.9 KB; binsort blocks alias it

    const int tid = threadIdx.x;

    if (blockIdx.x < NBIN) {
        // ----------------------- binsort part ----------------------------
        int*    cnt2 = (int*)Wt;                 // 256 ints @ 0
        int*    ex   = cnt2 + 256;               // 256 ints @ 1 KB
        int*    wsum = ex + 256;                 // 4 ints   @ 2 KB
        ushort* stgt = (ushort*)(wsum + 8);      // 10 KB    @ 2080 B (fits 36.9 KB)

        const int b = blockIdx.x;
        const int t = tid;
        const int lane = t & 63;
        const int wid  = t >> 6;
        int n_e = bin_cursor[b];
        n_e = (n_e < BINCAP) ? n_e : BINCAP;

        cnt2[t] = 0;
        __syncthreads();

        unsigned pk[20];                   // (tgt<<16)|(rank<<8)|node8
        int npk = 0;
        for (int i = t; i < n_e; i += 256) {
            unsigned v = slab[b * BINCAP + i];
            int node8 = v & 255u;
            int r = atomicAdd(&cnt2[node8], 1);
            r = (r < 255) ? r : 255;
            pk[npk++] = (v & 0xFFFF0000u) | ((unsigned)r << 8) | (unsigned)node8;
        }
        __syncthreads();

        // wave-level inclusive scan over 64 lanes (shuffles unconditional)
        const int v = cnt2[t];
        int x = v;
#pragma unroll
        for (int off = 1; off < 64; off <<= 1) {
            int y = __shfl_up(x, off);
            x += (lane >= off) ? y : 0;
        }
        if (lane == 63) wsum[wid] = x;
        __syncthreads();
        int add = 0;
#pragma unroll
        for (int w = 0; w < 4; ++w) add += (w < wid) ? wsum[w] : 0;
        const int myex = x + add - v;       // exclusive prefix
        const int mycnt = v;
        ex[t] = myex;
        __syncthreads();

        for (int j = 0; j < npk; ++j) {
            unsigned pv = pk[j];
            int lpos = ex[pv & 255u] + (int)((pv >> 8) & 255u);
            if (lpos < BINCAP) stgt[lpos] = (ushort)(pv >> 16);
        }
        __syncthreads();

        for (int i = t; i < n_e; i += 256) csr[b * BINCAP + i] = stgt[i];
        int node = b * 256 + t;
        if (node < N_NODES) {
            offs[node] = b * BINCAP + myex;
            deg[node]  = mycnt;
        }
        return;
    }

    // ------------------------- proj part ---------------------------------
    for (int idx = tid; idx < 64 * 128; idx += 256) {
        int kp = idx >> 7;
        int c  = idx & 127;
        float w0 = W[(2 * kp) * PROJ_DIM + c];
        float w1 = W[(2 * kp + 1) * PROJ_DIM + c];
        unsigned pr = (unsigned)f32_to_bf16(w0) | ((unsigned)f32_to_bf16(w1) << 16);
        *(unsigned*)&Wt[c * WSTR + 2 * kp] = pr;
    }
    __syncthreads();

    const int wv   = tid >> 6;
    const int lane = tid & 63;
    const int m = lane & 15;
    const int q = lane >> 4;
    const int rbase = (blockIdx.x - NBIN) * 128;

    int arow0 = rbase + wv * 32 + m;
    int arow1 = arow0 + 16;
    arow0 = (arow0 < N_NODES) ? arow0 : N_NODES - 1;
    arow1 = (arow1 < N_NODES) ? arow1 : N_NODES - 1;
    const long long xb0 = (long long)arow0 * IN_DIM;
    const long long xb1 = (long long)arow1 * IN_DIM;

    f32x4 acc[2][8];
#pragma unroll
    for (int rt = 0; rt < 2; ++rt)
#pragma unroll
        for (int ct = 0; ct < 8; ++ct) acc[rt][ct] = (f32x4){0.f, 0.f, 0.f, 0.f};

#pragma unroll
    for (int ks = 0; ks < 4; ++ks) {
        const int k0 = ks * 32 + q * 8;
        float4 a0lo = *(const float4*)&X[xb0 + k0];
        float4 a0hi = *(const float4*)&X[xb0 + k0 + 4];
        float4 a1lo = *(const float4*)&X[xb1 + k0];
        float4 a1hi = *(const float4*)&X[xb1 + k0 + 4];
        bf16x8 afrag0 = cvt8(a0lo, a0hi);
        bf16x8 afrag1 = cvt8(a1lo, a1hi);
#pragma unroll
        for (int ct = 0; ct < 8; ++ct) {
            bf16x8 bfrag = *(const bf16x8*)&Wt[(ct * 16 + m) * WSTR + k0];
            acc[0][ct] = __builtin_amdgcn_mfma_f32_16x16x32_bf16(afrag0, bfrag, acc[0][ct], 0, 0, 0);
            acc[1][ct] = __builtin_amdgcn_mfma_f32_16x16x32_bf16(afrag1, bfrag, acc[1][ct], 0, 0, 0);
        }
    }

    const float as_lo = att[m],      as_hi = att[m + 16];
    const float at_lo = att[32 + m], at_hi = att[48 + m];

#pragma unroll
    for (int rt = 0; rt < 2; ++rt) {
        const int rowb = rbase + wv * 32 + rt * 16 + q * 4;
#pragma unroll
        for (int r = 0; r < 4; ++r) {
            const int row = rowb + r;
            float cl[4], ch[4];
#pragma unroll
            for (int h = 0; h < 4; ++h) {
                cl[h] = acc[rt][2 * h][r];
                ch[h] = acc[rt][2 * h + 1][r];
            }
            if (row < N_NODES) {
                ushort4 plo, phi;
                plo.x = f32_to_f16(cl[0]); plo.y = f32_to_f16(cl[1]);
                plo.z = f32_to_f16(cl[2]); plo.w = f32_to_f16(cl[3]);
                phi.x = f32_to_f16(ch[0]); phi.y = f32_to_f16(ch[1]);
                phi.z = f32_to_f16(ch[2]); phi.w = f32_to_f16(ch[3]);
                *(ushort4*)&projT[(long long)row * PROJ_DIM + m * 4] = plo;
                *(ushort4*)&projT[(long long)row * PROJ_DIM + (m + 16) * 4] = phi;
            }
            float ps[4], pt[4];
#pragma unroll
            for (int h = 0; h < 4; ++h) {
                ps[h] = cl[h] * as_lo + ch[h] * as_hi;
                pt[h] = cl[h] * at_lo + ch[h] * at_hi;
            }
#pragma unroll
            for (int off = 8; off > 0; off >>= 1) {
#pragma unroll
                for (int h = 0; h < 4; ++h) {
                    ps[h] += __shfl_down(ps[h], off, 16);
                    pt[h] += __shfl_down(pt[h], off, 16);
                }
            }
            if (m == 0 && row < N_NODES) {
                *(float4*)&s_src[row * N_HEADS] = make_float4(ps[0], ps[1], ps[2], ps[3]);
                *(float4*)&s_tgt[row * N_HEADS] = make_float4(pt[0], pt[1], pt[2], pt[3]);
            }
        }
    }
}

// ---------------------------------------------------------------------------
// K3: gather v8 — R7 inner loop (proven best) wrapped in a GRID-STRIDE outer
//   loop: 2048 blocks (exactly 32 waves/CU requested) sweep the 12500 node
//   groups, keeping waves RESIDENT instead of launching 12500 short-lived
//   blocks (measured OccupancyPercent was 56% despite VGPR/LDS allowing
//   full occupancy -> workgroup fill/drain rate suspected). Inner code is
//   byte-identical to R7; edata reuse across groups is same-wave sequential
//   (lgkmcnt-ordered), no barrier needed.
// ---------------------------------------------------------------------------
__global__ __launch_bounds__(256) void gather_kernel(
    const int* __restrict__ deg, const int* __restrict__ offs,
    const ushort* __restrict__ csr,
    const float* __restrict__ s_src, const float* __restrict__ s_tgt,
    const ushort* __restrict__ projT, float* __restrict__ out)
{
    __shared__ uint4 edata[4][MAXDEG];     // 4 waves x 64 slots x 16 B = 4 KB

    const int wv   = threadIdx.x >> 6;
    const int lane = threadIdx.x & 63;
    const int d    = lane & 31;
    const int half = lane >> 5;

    for (int grp = blockIdx.x; grp < NGROUPS; grp += GATHER_BLKS) {
        const int node = grp * 4 + wv;      // N_NODES = 12500*4

        int n = deg[node];
        n = (n < MAXDEG) ? n : MAXDEG;
        const int o = offs[node];

        uint4 ed = make_uint4(0u, 0u, 0u, 0u);
        if (lane < n) {
            int tgt = csr[o + lane];                            // coalesced ushort
            float4 ss = *(const float4*)&s_src[node * N_HEADS]; // wave-uniform
            float4 st = *(const float4*)&s_tgt[tgt * N_HEADS];  // parallel gather

            float sc[4] = { ss.x + st.x, ss.y + st.y, ss.z + st.z, ss.w + st.w };
            float mx = -1e30f;
#pragma unroll
            for (int h = 0; h < 4; ++h) {
                sc[h] = (sc[h] > 0.0f) ? sc[h] : 0.01f * sc[h];  // leaky_relu
                mx = fmaxf(mx, sc[h]);
            }
            float sum = 0.0f;
#pragma unroll
            for (int h = 0; h < 4; ++h) {
                sc[h] = __expf(sc[h] - mx);
                sum += sc[h];
            }
            float inv = 0.25f / sum;     // softmax normalize * head-mean

            h2 a01, a23;
            a01.x = (_Float16)(sc[0] * inv);
            a01.y = (_Float16)(sc[1] * inv);
            a23.x = (_Float16)(sc[2] * inv);
            a23.y = (_Float16)(sc[3] * inv);
            ed.x = (unsigned)tgt;
            ed.y = __builtin_bit_cast(unsigned, a01);
            ed.z = __builtin_bit_cast(unsigned, a23);
        }
        edata[wv][lane] = ed;            // all 64 lanes write (dead slots zeroed)
        // no barrier: same wave produces and consumes (lgkmcnt ordering)

        float acc0 = 0.0f, acc1 = 0.0f, acc2 = 0.0f, acc3 = 0.0f;

        // 16 edge slots per iteration (8 per half), 8 outstanding projT
        // gathers per lane; slot metadata via broadcast ds_read_b128.
        for (int j = 0; j < n; j += 16) {
            uint4 s[8];
#pragma unroll
            for (int u = 0; u < 8; ++u)
                s[u] = edata[wv][j + 2 * u + half];   // half-uniform broadcast
            uint2 p[8];
#pragma unroll
            for (int u = 0; u < 8; ++u)
                p[u] = *(const uint2*)&projT[(long long)s[u].x * PROJ_DIM + d * 4];
#pragma unroll
            for (int u = 0; u < 8; ++u) {
                h2 a  = __builtin_bit_cast(h2, s[u].y);
                h2 b  = __builtin_bit_cast(h2, s[u].z);
                h2 lo = __builtin_bit_cast(h2, p[u].x);
                h2 hi = __builtin_bit_cast(h2, p[u].y);
                float* accp = (u & 1) ? ((u & 2) ? &acc3 : &acc1)
                                      : ((u & 2) ? &acc2 : &acc0);
                float tt = *accp;
#if __has_builtin(__builtin_amdgcn_fdot2)
                tt = __builtin_amdgcn_fdot2(a, lo, tt, false);   // v_dot2_f32_f16
                tt = __builtin_amdgcn_fdot2(b, hi, tt, false);
#else
                tt = fmaf((float)a.x, (float)lo.x, tt);          // v_fma_mix_f32
                tt = fmaf((float)a.y, (float)lo.y, tt);
                tt = fmaf((float)b.x, (float)hi.x, tt);
                tt = fmaf((float)b.y, (float)hi.y, tt);
#endif
                *accp = tt;
            }
        }

        float acc = (acc0 + acc1) + (acc2 + acc3);
        acc += __shfl_down(acc, 32);      // combine the two halves (width 64)
        if (lane < 32) out[node * OUT_DIM + d] = acc;
    }
}

extern "C" void kernel_launch(void* const* d_in, const int* in_sizes, int n_in,
                              void* d_out, int out_size, void* d_ws, size_t ws_size,
                              hipStream_t stream) {
    const float* X   = (const float*)d_in[0];
    const int*   ei  = (const int*)d_in[1];
    const float* W   = (const float*)d_in[2];
    const float* att = (const float*)d_in[3];
    float* out = (float*)d_out;

    // workspace layout, total ~20.8 MB
    char* p = (char*)d_ws;
    ushort* projT   = (ushort*)p;   p += (size_t)N_NODES * PROJ_DIM * 2;  // 12.8 MB
    float* s_src    = (float*)p;    p += (size_t)N_NODES * N_HEADS * 4;   // 0.8 MB
    float* s_tgt    = (float*)p;    p += (size_t)N_NODES * N_HEADS * 4;   // 0.8 MB
    unsigned* slab  = (unsigned*)p; p += (size_t)NBIN * BINCAP * 4;       // 3.92 MB
    ushort* csr     = (ushort*)p;   p += (size_t)NBIN * BINCAP * 2;       // 1.96 MB
    int* offs       = (int*)p;      p += (size_t)N_NODES * 4;             // 0.2 MB
    int* deg        = (int*)p;      p += (size_t)N_NODES * 4;             // 0.2 MB
    int* bin_cursor = (int*)p;      p += 256 * 4;

    (void)hipMemsetAsync(bin_cursor, 0, 256 * sizeof(int), stream);

    partition_kernel<<<PART_BLKS, 256, 0, stream>>>(ei, bin_cursor, slab);

    fused_kernel<<<FUSE_BLKS, 256, 0, stream>>>(
        X, W, att, slab, bin_cursor, projT, s_src, s_tgt, csr, offs, deg);

    gather_kernel<<<GATHER_BLKS, 256, 0, stream>>>(
        deg, offs, csr, s_src, s_tgt, projT, out);
}